// Round 10
// baseline (107.163 us; speedup 1.0000x reference)
//
#include <hip/hip_runtime.h>
#include <stdint.h>

typedef unsigned long long u64;
typedef unsigned int u32;

#define CONF_T 0.9f
#define IOU_T 0.5f
#define TOPK 4096
#define CAP 384            // per-bin segment capacity (expected ~84, max ~140)

// ---- workspace layout (bytes) ----
#define BINCNT_OFF 0         // u32[4096]       16384
#define VALIDW_OFF 16384     // u64[64]         512
#define NZW_OFF    16896     // u64[64]         512
#define SELBOX_OFF 32768     // float4[4096]    65536
#define SELSC_OFF  98304     // float[4096]     16384
#define SELLM_OFF  114688    // float[40960]    163840
#define MASK_OFF   278528    // u64[4096*64]    2097152
#define BINSEG_OFF 2375680   // u64[4096*384]   12582912

__device__ __forceinline__ int score_bin(float s) {
    u32 b = __float_as_uint(s);
    if (b >= 0x3F800000u) return 0;
    int bin = (int)((0x3F800000u - b) >> 9);
    return bin > 4095 ? 4095 : bin;
}

// K0: zero binCnt + validw/nzw
__global__ void k_zero(u32* __restrict__ binCnt, u64* __restrict__ validw,
                       u64* __restrict__ nzw) {
    int i = blockIdx.x * 256 + threadIdx.x;
    binCnt[i] = 0u;
    if (i < 64) { validw[i] = 0ull; nzw[i] = 0ull; }
}

// K1: single conf scan, candidates scattered directly into per-bin segments.
__global__ void __launch_bounds__(256) k_compact(
        const float4* __restrict__ conf4, int N2,
        u32* __restrict__ binCnt, u64* __restrict__ binseg) {
    int stride = gridDim.x * 256;
    for (int i = blockIdx.x * 256 + threadIdx.x; i < N2; i += stride) {
        float4 v = conf4[i];
        if (v.y > CONF_T) {
            int b = score_bin(v.y);
            u32 p = atomicAdd(&binCnt[b], 1u);
            if (p < CAP)
                binseg[(size_t)b * CAP + p] =
                    ((u64)__float_as_uint(v.y) << 32) | (u64)(~(u32)(2 * i));
        }
        if (v.w > CONF_T) {
            int b = score_bin(v.w);
            u32 p = atomicAdd(&binCnt[b], 1u);
            if (p < CAP)
                binseg[(size_t)b * CAP + p] =
                    ((u64)__float_as_uint(v.w) << 32) | (u64)(~(u32)(2 * i + 1));
        }
    }
}

// K2: per-block redundant prefix scan of binCnt in LDS, exact rank within bin,
// decode, scatter to rank position, AND write the output row (nms zeroes later).
__global__ void __launch_bounds__(256) k_rankscan(
        const float4* __restrict__ loc, const float4* __restrict__ priors,
        const float* __restrict__ landm, const u32* __restrict__ binCnt,
        const u64* __restrict__ binseg,
        float4* __restrict__ selbox, float* __restrict__ selscore,
        float* __restrict__ sellm, float* __restrict__ out) {
    __shared__ u32 pref_s[4097];
    __shared__ u32 parts[256];
    __shared__ u32 m_sh;
    int t = threadIdx.x;
    u32 h[16];
    u32 sum = 0;
    #pragma unroll
    for (int i = 0; i < 16; i++) {
        u32 c = binCnt[t * 16 + i];
        h[i] = c > CAP ? CAP : c;
        sum += h[i];
    }
    parts[t] = sum;
    if (t == 0) m_sh = 0u;
    __syncthreads();
    for (int d = 1; d < 256; d <<= 1) {
        u32 add = (t >= d) ? parts[t - d] : 0u;
        __syncthreads();
        parts[t] += add;
        __syncthreads();
    }
    u32 incl = parts[t];
    u32 excl = incl - sum;
    u32 run = excl;
    #pragma unroll
    for (int i = 0; i < 16; i++) { pref_s[t * 16 + i] = run; run += h[i]; }
    if (t == 255) pref_s[4096] = run;   // total
    __syncthreads();
    u32 total = pref_s[4096];
    u32 target = total < TOPK ? total : TOPK;
    if (total > 0 && excl < target && incl >= target) {
        u32 r2 = excl;
        #pragma unroll
        for (int i = 0; i < 16; i++) {
            r2 += h[i];
            if (r2 >= target) { m_sh = r2; break; }
        }
    }
    __syncthreads();
    u32 M = m_sh;
    u32 p = blockIdx.x * 256 + t;
    if (p >= M) {
        if (p < TOPK) {   // zero-pad unused ranks (sel + out row)
            selbox[p] = make_float4(0.f, 0.f, 0.f, 0.f);
            selscore[p] = 0.f;
            #pragma unroll
            for (int q = 0; q < 10; q++) sellm[(size_t)p * 10 + q] = 0.f;
            float* o = out + (size_t)p * 15;
            #pragma unroll
            for (int q = 0; q < 15; q++) o[q] = 0.f;
        }
        return;
    }
    int lo = 0, hi = 4095;   // largest bin with pref_s[bin] <= p
    while (lo < hi) {
        int mid = (lo + hi + 1) >> 1;
        if (pref_s[mid] <= p) lo = mid; else hi = mid - 1;
    }
    u32 st = pref_s[lo];
    u32 cnt = pref_s[lo + 1] - st;
    const u64* seg = binseg + (size_t)lo * CAP;
    u64 key = seg[p - st];
    u32 rank = st;
    for (u32 j = 0; j < cnt; j++) rank += (seg[j] > key) ? 1u : 0u;
    if (rank >= TOPK) return;
    u32 idx = ~(u32)key;
    float sc = __uint_as_float((u32)(key >> 32));
    float4 L = loc[idx];
    float4 P = priors[idx];
    float cx = P.x + L.x * 0.1f * P.z;
    float cy = P.y + L.y * 0.1f * P.w;
    float wx = P.z * expf(L.z * 0.2f);
    float wy = P.w * expf(L.w * 0.2f);
    float4 bx;
    bx.x = (cx - 0.5f * wx) * 8192.f;
    bx.y = (cy - 0.5f * wy) * 8192.f;
    bx.z = (cx + 0.5f * wx) * 8192.f;
    bx.w = (cy + 0.5f * wy) * 8192.f;
    selbox[rank] = bx;
    selscore[rank] = sc;
    const float* lmr = landm + (size_t)idx * 10;
    float* lmo = sellm + (size_t)rank * 10;
    float* o = out + (size_t)rank * 15;
    o[0] = bx.x; o[1] = bx.y; o[2] = bx.z; o[3] = bx.w; o[4] = sc;
    #pragma unroll
    for (int q = 0; q < 5; q++) {
        float lx = lmr[2 * q], ly = lmr[2 * q + 1];
        float ox = (P.x + lx * 0.1f * P.z) * 8192.f;
        float oy = (P.y + ly * 0.1f * P.w) * 8192.f;
        lmo[2 * q] = ox; lmo[2 * q + 1] = oy;
        o[5 + 2 * q] = ox; o[6 + 2 * q] = oy;
    }
}

// K3: mask matrix, triangle-balanced: wave wid handles rows
// {wid, 2047-wid, 2048+wid, 4095-wid} — exactly 130 column-words per wave.
// Each row loops only w in [row>>6, 64); all 64 words stored (zeros included).
__global__ void __launch_bounds__(256) k_maskbal(
        const float4* __restrict__ selbox, const float* __restrict__ selscore,
        u64* __restrict__ mask, u64* __restrict__ validw, u64* __restrict__ nzw) {
    __shared__ float4 sb[TOPK];   // 64 KB
    int t = threadIdx.x, b = blockIdx.x;
    for (int i = t; i < TOPK; i += 256) sb[i] = selbox[i];
    __syncthreads();
    int wv = t >> 6, lane = t & 63;
    int wid = b * 4 + wv;                 // 0..1023
    int rows[4] = { wid, 2047 - wid, 2048 + wid, 4095 - wid };
    #pragma unroll
    for (int q = 0; q < 4; q++) {
        int row = rows[q];
        float4 ri = sb[row];
        float ai = fmaxf(ri.z - ri.x, 0.f) * fmaxf(ri.w - ri.y, 0.f);
        u64 myword = 0ull;
        int wstart = row >> 6;
        for (int w = wstart; w < 64; w++) {
            int j = w * 64 + lane;
            float4 bj = sb[j];
            float aj = fmaxf(bj.z - bj.x, 0.f) * fmaxf(bj.w - bj.y, 0.f);
            float lx = fmaxf(ri.x, bj.x), ly = fmaxf(ri.y, bj.y);
            float rx = fminf(ri.z, bj.z), ry = fminf(ri.w, bj.w);
            float inter = fmaxf(rx - lx, 0.f) * fmaxf(ry - ly, 0.f);
            float iou = inter / (ai + aj - inter + 1e-12f);
            bool pred = (j > row) && (iou > IOU_T);
            u64 bb = __ballot(pred);
            if (lane == w) myword = bb;
        }
        mask[(size_t)row * 64 + lane] = myword;   // zeros for lane < wstart
        u64 nzb = __ballot(myword != 0ull);
        if (lane == 0) {
            bool v = selscore[row] > CONF_T;
            int g = row >> 6, sh = row & 63;
            if (v)   atomicOr(&validw[g], 1ull << sh);
            if (nzb) atomicOr(&nzw[g], 1ull << sh);
        }
    }
}

// K4: serial greedy NMS (wave 0) + zero suppressed/invalid output rows (4 waves)
__global__ void __launch_bounds__(256) k_nms(
        const u64* __restrict__ mask, const u64* __restrict__ validw_arr,
        const u64* __restrict__ nzw_arr, float* __restrict__ out) {
    __shared__ u64 keep_s[64];
    int tid = threadIdx.x;
    if (tid < 64) {
        int t = tid;
        u64 vw = validw_arr[t];
        u64 nzv = nzw_arr[t];
        u64 sup = 0ull, keepw = 0ull;
        for (int g = 0; g < 64; g++) {
            u64 cur = __shfl(sup, g);
            u64 validg = __shfl(vw, g);
            u64 nzg = __shfl(nzv, g);
            u64 alive = (~cur) & validg;
            if (nzg) {
                u64 intra = mask[(size_t)(g * 64 + t) * 64 + g];
                u64 rem = nzg;
                while (rem) {
                    int bb = __ffsll((long long)rem) - 1;
                    rem &= rem - 1;
                    if ((alive >> bb) & 1ull) {
                        u64 rowb = __shfl(intra, bb);
                        alive &= ~rowb;
                    }
                }
            }
            if (t == g) keepw = alive;
            u64 srem = alive & nzg;
            const u64* mb = mask + (size_t)(g * 64) * 64 + t;
            while (srem) {
                int i0, i1 = -1, i2 = -1, i3 = -1, i4 = -1, i5 = -1, i6 = -1, i7 = -1;
                i0 = __ffsll((long long)srem) - 1; srem &= srem - 1;
                if (srem) { i1 = __ffsll((long long)srem) - 1; srem &= srem - 1;
                if (srem) { i2 = __ffsll((long long)srem) - 1; srem &= srem - 1;
                if (srem) { i3 = __ffsll((long long)srem) - 1; srem &= srem - 1;
                if (srem) { i4 = __ffsll((long long)srem) - 1; srem &= srem - 1;
                if (srem) { i5 = __ffsll((long long)srem) - 1; srem &= srem - 1;
                if (srem) { i6 = __ffsll((long long)srem) - 1; srem &= srem - 1;
                if (srem) { i7 = __ffsll((long long)srem) - 1; srem &= srem - 1; } } } } } } }
                u64 a0 = mb[(size_t)i0 * 64];
                u64 a1 = (i1 >= 0) ? mb[(size_t)i1 * 64] : 0ull;
                u64 a2 = (i2 >= 0) ? mb[(size_t)i2 * 64] : 0ull;
                u64 a3 = (i3 >= 0) ? mb[(size_t)i3 * 64] : 0ull;
                u64 a4 = (i4 >= 0) ? mb[(size_t)i4 * 64] : 0ull;
                u64 a5 = (i5 >= 0) ? mb[(size_t)i5 * 64] : 0ull;
                u64 a6 = (i6 >= 0) ? mb[(size_t)i6 * 64] : 0ull;
                u64 a7 = (i7 >= 0) ? mb[(size_t)i7 * 64] : 0ull;
                sup |= (a0 | a1) | (a2 | a3) | ((a4 | a5) | (a6 | a7));
            }
        }
        keep_s[t] = keepw;
    }
    __syncthreads();
    for (int r = tid; r < TOPK; r += 256) {
        if (!((keep_s[r >> 6] >> (r & 63)) & 1ull)) {
            float* o = out + (size_t)r * 15;
            #pragma unroll
            for (int q = 0; q < 15; q++) o[q] = 0.f;
        }
    }
}

extern "C" void kernel_launch(void* const* d_in, const int* in_sizes, int n_in,
                              void* d_out, int out_size, void* d_ws, size_t ws_size,
                              hipStream_t stream) {
    const float4* loc    = (const float4*)d_in[0];
    const float4* conf4  = (const float4*)d_in[1];
    const float*  landm  = (const float*)d_in[2];
    const float4* priors = (const float4*)d_in[3];
    float* out = (float*)d_out;
    int N = in_sizes[1] / 2;
    int N2 = N / 2;   // float4 elements (2 anchors each)

    char* ws = (char*)d_ws;
    u32* binCnt   = (u32*)(ws + BINCNT_OFF);
    u64* validw   = (u64*)(ws + VALIDW_OFF);
    u64* nzw      = (u64*)(ws + NZW_OFF);
    float4* selbox = (float4*)(ws + SELBOX_OFF);
    float* selsc   = (float*)(ws + SELSC_OFF);
    float* sellm   = (float*)(ws + SELLM_OFF);
    u64* maskp    = (u64*)(ws + MASK_OFF);
    u64* binseg   = (u64*)(ws + BINSEG_OFF);

    k_zero<<<16, 256, 0, stream>>>(binCnt, validw, nzw);
    k_compact<<<1024, 256, 0, stream>>>(conf4, N2, binCnt, binseg);
    k_rankscan<<<32, 256, 0, stream>>>(loc, priors, landm, binCnt, binseg,
                                       selbox, selsc, sellm, out);
    k_maskbal<<<256, 256, 0, stream>>>(selbox, selsc, maskp, validw, nzw);
    k_nms<<<1, 256, 0, stream>>>(maskp, validw, nzw, out);
}

// Round 11
// 94.561 us; speedup vs baseline: 1.1333x; 1.1333x over previous
//
#include <hip/hip_runtime.h>
#include <stdint.h>

typedef unsigned long long u64;
typedef unsigned int u32;

#define CONF_T 0.9f
#define IOU_T 0.5f
#define TOPK 4096
#define CAP 384            // per-bin segment capacity (expected ~84, max ~140)

// ---- workspace layout (bytes) ----
#define BINCNT_OFF 0         // u32[4096]       16384
#define VALIDW_OFF 16384     // u64[64]         512
#define NZW_OFF    16896     // u64[64]         512
#define SELBOX_OFF 32768     // float4[4096]    65536
#define SELSC_OFF  98304     // float[4096]     16384
#define SELLM_OFF  114688    // float[40960]    163840
#define MASK_OFF   278528    // u64[4096*64]    2097152
#define BINSEG_OFF 2375680   // u64[4096*384]   12582912

__device__ __forceinline__ int score_bin(float s) {
    u32 b = __float_as_uint(s);
    if (b >= 0x3F800000u) return 0;
    int bin = (int)((0x3F800000u - b) >> 9);
    return bin > 4095 ? 4095 : bin;
}

// K0: zero binCnt + validw/nzw
__global__ void k_zero(u32* __restrict__ binCnt, u64* __restrict__ validw,
                       u64* __restrict__ nzw) {
    int i = blockIdx.x * 256 + threadIdx.x;
    binCnt[i] = 0u;
    if (i < 64) { validw[i] = 0ull; nzw[i] = 0ull; }
}

// K1: single conf scan, candidates scattered directly into per-bin segments.
__global__ void __launch_bounds__(256) k_compact(
        const float4* __restrict__ conf4, int N2,
        u32* __restrict__ binCnt, u64* __restrict__ binseg) {
    int stride = gridDim.x * 256;
    for (int i = blockIdx.x * 256 + threadIdx.x; i < N2; i += stride) {
        float4 v = conf4[i];
        if (v.y > CONF_T) {
            int b = score_bin(v.y);
            u32 p = atomicAdd(&binCnt[b], 1u);
            if (p < CAP)
                binseg[(size_t)b * CAP + p] =
                    ((u64)__float_as_uint(v.y) << 32) | (u64)(~(u32)(2 * i));
        }
        if (v.w > CONF_T) {
            int b = score_bin(v.w);
            u32 p = atomicAdd(&binCnt[b], 1u);
            if (p < CAP)
                binseg[(size_t)b * CAP + p] =
                    ((u64)__float_as_uint(v.w) << 32) | (u64)(~(u32)(2 * i + 1));
        }
    }
}

// K2: per-block redundant prefix scan of binCnt in LDS, then exact rank within
// bin + decode + scatter to rank position; threads beyond M zero-pad.
__global__ void __launch_bounds__(256) k_rankscan(
        const float4* __restrict__ loc, const float4* __restrict__ priors,
        const float* __restrict__ landm, const u32* __restrict__ binCnt,
        const u64* __restrict__ binseg,
        float4* __restrict__ selbox, float* __restrict__ selscore,
        float* __restrict__ sellm) {
    __shared__ u32 pref_s[4097];
    __shared__ u32 parts[256];
    __shared__ u32 m_sh;
    int t = threadIdx.x;
    u32 h[16];
    u32 sum = 0;
    #pragma unroll
    for (int i = 0; i < 16; i++) {
        u32 c = binCnt[t * 16 + i];
        h[i] = c > CAP ? CAP : c;
        sum += h[i];
    }
    parts[t] = sum;
    if (t == 0) m_sh = 0u;
    __syncthreads();
    for (int d = 1; d < 256; d <<= 1) {
        u32 add = (t >= d) ? parts[t - d] : 0u;
        __syncthreads();
        parts[t] += add;
        __syncthreads();
    }
    u32 incl = parts[t];
    u32 excl = incl - sum;
    u32 run = excl;
    #pragma unroll
    for (int i = 0; i < 16; i++) { pref_s[t * 16 + i] = run; run += h[i]; }
    if (t == 255) pref_s[4096] = run;   // total
    __syncthreads();
    u32 total = pref_s[4096];
    u32 target = total < TOPK ? total : TOPK;
    if (total > 0 && excl < target && incl >= target) {
        u32 r2 = excl;
        #pragma unroll
        for (int i = 0; i < 16; i++) {
            r2 += h[i];
            if (r2 >= target) { m_sh = r2; break; }
        }
    }
    __syncthreads();
    u32 M = m_sh;
    u32 p = blockIdx.x * 256 + t;
    if (p >= M) {
        if (p < TOPK) {   // zero-pad unused ranks
            selbox[p] = make_float4(0.f, 0.f, 0.f, 0.f);
            selscore[p] = 0.f;
            #pragma unroll
            for (int q = 0; q < 10; q++) sellm[(size_t)p * 10 + q] = 0.f;
        }
        return;
    }
    int lo = 0, hi = 4095;   // largest bin with pref_s[bin] <= p
    while (lo < hi) {
        int mid = (lo + hi + 1) >> 1;
        if (pref_s[mid] <= p) lo = mid; else hi = mid - 1;
    }
    u32 st = pref_s[lo];
    u32 cnt = pref_s[lo + 1] - st;
    const u64* seg = binseg + (size_t)lo * CAP;
    u64 key = seg[p - st];
    u32 rank = st;
    for (u32 j = 0; j < cnt; j++) rank += (seg[j] > key) ? 1u : 0u;
    if (rank >= TOPK) return;
    u32 idx = ~(u32)key;
    float sc = __uint_as_float((u32)(key >> 32));
    float4 L = loc[idx];
    float4 P = priors[idx];
    float cx = P.x + L.x * 0.1f * P.z;
    float cy = P.y + L.y * 0.1f * P.w;
    float wx = P.z * expf(L.z * 0.2f);
    float wy = P.w * expf(L.w * 0.2f);
    float4 bx;
    bx.x = (cx - 0.5f * wx) * 8192.f;
    bx.y = (cy - 0.5f * wy) * 8192.f;
    bx.z = (cx + 0.5f * wx) * 8192.f;
    bx.w = (cy + 0.5f * wy) * 8192.f;
    selbox[rank] = bx;
    selscore[rank] = sc;
    const float* lmr = landm + (size_t)idx * 10;
    float* lmo = sellm + (size_t)rank * 10;
    #pragma unroll
    for (int q = 0; q < 5; q++) {
        float lx = lmr[2 * q], ly = lmr[2 * q + 1];
        lmo[2 * q]     = (P.x + lx * 0.1f * P.z) * 8192.f;
        lmo[2 * q + 1] = (P.y + ly * 0.1f * P.w) * 8192.f;
    }
}

// K3: mask matrix, balanced + amortized: block b owns top rows 8b..8b+7 and
// bottom rows 4088-8b..4095-8b. Each wave: a top pair + a bottom pair, looping
// w from (pair_row>>6) with the sb[j] load amortized over the 2 rows.
// Per-wave work is ~65 iterations for EVERY block (R7 worst was 64x4).
// Also ORs valid/nonzero bits and writes this block's 16 output rows.
__global__ void __launch_bounds__(256) k_maskout(
        const float4* __restrict__ selbox, const float* __restrict__ selscore,
        const float* __restrict__ sellm,
        u64* __restrict__ mask, u64* __restrict__ validw, u64* __restrict__ nzw,
        float* __restrict__ out) {
    __shared__ float4 sb[TOPK];   // 64 KB
    int t = threadIdx.x, b = blockIdx.x;
    for (int i = t; i < TOPK; i += 256) sb[i] = selbox[i];
    __syncthreads();
    int wv = t >> 6, lane = t & 63;
    #pragma unroll
    for (int ph = 0; ph < 2; ph++) {
        int r0 = (ph == 0) ? (b * 8 + wv * 2) : (4088 - 8 * b + wv * 2);
        int r1 = r0 + 1;
        float4 ra = sb[r0], rb = sb[r1];
        float aa = fmaxf(ra.z - ra.x, 0.f) * fmaxf(ra.w - ra.y, 0.f);
        float ab = fmaxf(rb.z - rb.x, 0.f) * fmaxf(rb.w - rb.y, 0.f);
        u64 w0 = 0ull, w1 = 0ull;
        int wstart = r0 >> 6;
        for (int w = wstart; w < 64; w++) {
            int j = w * 64 + lane;
            float4 bj = sb[j];
            float aj = fmaxf(bj.z - bj.x, 0.f) * fmaxf(bj.w - bj.y, 0.f);
            float lx0 = fmaxf(ra.x, bj.x), ly0 = fmaxf(ra.y, bj.y);
            float rx0 = fminf(ra.z, bj.z), ry0 = fminf(ra.w, bj.w);
            float in0 = fmaxf(rx0 - lx0, 0.f) * fmaxf(ry0 - ly0, 0.f);
            float iou0 = in0 / (aa + aj - in0 + 1e-12f);
            u64 bb0 = __ballot((j > r0) && (iou0 > IOU_T));
            float lx1 = fmaxf(rb.x, bj.x), ly1 = fmaxf(rb.y, bj.y);
            float rx1 = fminf(rb.z, bj.z), ry1 = fminf(rb.w, bj.w);
            float in1 = fmaxf(rx1 - lx1, 0.f) * fmaxf(ry1 - ly1, 0.f);
            float iou1 = in1 / (ab + aj - in1 + 1e-12f);
            u64 bb1 = __ballot((j > r1) && (iou1 > IOU_T));
            if (lane == w) { w0 = bb0; w1 = bb1; }
        }
        mask[(size_t)r0 * 64 + lane] = w0;   // zeros for lane < wstart
        mask[(size_t)r1 * 64 + lane] = w1;
        u64 nz0 = __ballot(w0 != 0ull), nz1 = __ballot(w1 != 0ull);
        u64 vb = __ballot(lane < 2 && selscore[r0 + lane] > CONF_T);  // bits 0..1
        if (lane == 0) {
            int g = r0 >> 6, sh = r0 & 63;   // r0 even, sh <= 62: r1 same group
            u64 nzb = (nz0 ? 1ull : 0) | (nz1 ? 2ull : 0);
            if (vb)  atomicOr(&validw[g], vb << sh);
            if (nzb) atomicOr(&nzw[g], nzb << sh);
        }
    }
    // unconditional output write for this block's 16 rows (nms zeroes later)
    if (t < 240) {
        int ri = t / 15;
        int col = t - ri * 15;
        int row = (ri < 8) ? (b * 8 + ri) : (4088 - 8 * b + (ri - 8));
        const float* sbf = (const float*)selbox;
        float val;
        if (col < 4)       val = sbf[row * 4 + col];
        else if (col == 4) val = selscore[row];
        else               val = sellm[(size_t)row * 10 + (col - 5)];
        out[(size_t)row * 15 + col] = val;
    }
}

// K4: serial greedy NMS (wave 0) + zeroing of non-kept rows (all 16 waves)
__global__ void __launch_bounds__(1024) k_nmszero(
        const u64* __restrict__ mask, const u64* __restrict__ validw_arr,
        const u64* __restrict__ nzw_arr, float* __restrict__ out) {
    __shared__ u64 keep_s[64];
    int tid = threadIdx.x;
    if (tid < 64) {
        int t = tid;
        u64 vw = validw_arr[t];
        u64 nzv = nzw_arr[t];
        u64 sup = 0ull, keepw = 0ull;
        for (int g = 0; g < 64; g++) {
            u64 cur = __shfl(sup, g);
            u64 validg = __shfl(vw, g);
            u64 nzg = __shfl(nzv, g);
            u64 alive = (~cur) & validg;
            if (nzg) {
                u64 intra = mask[(size_t)(g * 64 + t) * 64 + g];
                u64 rem = nzg;
                while (rem) {
                    int bb = __ffsll((long long)rem) - 1;
                    rem &= rem - 1;
                    if ((alive >> bb) & 1ull) {
                        u64 rowb = __shfl(intra, bb);
                        alive &= ~rowb;
                    }
                }
            }
            if (t == g) keepw = alive;
            u64 srem = alive & nzg;
            const u64* mb = mask + (size_t)(g * 64) * 64 + t;
            while (srem) {
                int i0, i1 = -1, i2 = -1, i3 = -1, i4 = -1, i5 = -1, i6 = -1, i7 = -1;
                i0 = __ffsll((long long)srem) - 1; srem &= srem - 1;
                if (srem) { i1 = __ffsll((long long)srem) - 1; srem &= srem - 1;
                if (srem) { i2 = __ffsll((long long)srem) - 1; srem &= srem - 1;
                if (srem) { i3 = __ffsll((long long)srem) - 1; srem &= srem - 1;
                if (srem) { i4 = __ffsll((long long)srem) - 1; srem &= srem - 1;
                if (srem) { i5 = __ffsll((long long)srem) - 1; srem &= srem - 1;
                if (srem) { i6 = __ffsll((long long)srem) - 1; srem &= srem - 1;
                if (srem) { i7 = __ffsll((long long)srem) - 1; srem &= srem - 1; } } } } } } }
                u64 a0 = mb[(size_t)i0 * 64];
                u64 a1 = (i1 >= 0) ? mb[(size_t)i1 * 64] : 0ull;
                u64 a2 = (i2 >= 0) ? mb[(size_t)i2 * 64] : 0ull;
                u64 a3 = (i3 >= 0) ? mb[(size_t)i3 * 64] : 0ull;
                u64 a4 = (i4 >= 0) ? mb[(size_t)i4 * 64] : 0ull;
                u64 a5 = (i5 >= 0) ? mb[(size_t)i5 * 64] : 0ull;
                u64 a6 = (i6 >= 0) ? mb[(size_t)i6 * 64] : 0ull;
                u64 a7 = (i7 >= 0) ? mb[(size_t)i7 * 64] : 0ull;
                sup |= (a0 | a1) | (a2 | a3) | ((a4 | a5) | (a6 | a7));
            }
        }
        keep_s[t] = keepw;
    }
    __syncthreads();
    for (int r = tid; r < TOPK; r += 1024) {
        if (!((keep_s[r >> 6] >> (r & 63)) & 1ull)) {
            float* o = out + (size_t)r * 15;
            #pragma unroll
            for (int q = 0; q < 15; q++) o[q] = 0.f;
        }
    }
}

extern "C" void kernel_launch(void* const* d_in, const int* in_sizes, int n_in,
                              void* d_out, int out_size, void* d_ws, size_t ws_size,
                              hipStream_t stream) {
    const float4* loc    = (const float4*)d_in[0];
    const float4* conf4  = (const float4*)d_in[1];
    const float*  landm  = (const float*)d_in[2];
    const float4* priors = (const float4*)d_in[3];
    float* out = (float*)d_out;
    int N = in_sizes[1] / 2;
    int N2 = N / 2;   // float4 elements (2 anchors each)

    char* ws = (char*)d_ws;
    u32* binCnt   = (u32*)(ws + BINCNT_OFF);
    u64* validw   = (u64*)(ws + VALIDW_OFF);
    u64* nzw      = (u64*)(ws + NZW_OFF);
    float4* selbox = (float4*)(ws + SELBOX_OFF);
    float* selsc   = (float*)(ws + SELSC_OFF);
    float* sellm   = (float*)(ws + SELLM_OFF);
    u64* maskp    = (u64*)(ws + MASK_OFF);
    u64* binseg   = (u64*)(ws + BINSEG_OFF);

    k_zero<<<16, 256, 0, stream>>>(binCnt, validw, nzw);
    k_compact<<<2048, 256, 0, stream>>>(conf4, N2, binCnt, binseg);
    k_rankscan<<<32, 256, 0, stream>>>(loc, priors, landm, binCnt, binseg,
                                       selbox, selsc, sellm);
    k_maskout<<<256, 256, 0, stream>>>(selbox, selsc, sellm, maskp, validw, nzw, out);
    k_nmszero<<<1, 1024, 0, stream>>>(maskp, validw, nzw, out);
}

// Round 12
// 93.390 us; speedup vs baseline: 1.1475x; 1.0125x over previous
//
#include <hip/hip_runtime.h>
#include <stdint.h>

typedef unsigned long long u64;
typedef unsigned int u32;

#define CONF_T 0.9f
#define IOU_T 0.5f
#define TOPK 4096
#define CAP 384            // per-bin segment capacity (expected ~84, max ~140)

// ---- workspace layout (bytes) ----
#define BINCNT_OFF 0         // u32[4096]       16384
#define VALIDW_OFF 16384     // u64[64]         512
#define NZW_OFF    16896     // u64[64]         512
#define SELBOX_OFF 32768     // float4[4096]    65536
#define SELSC_OFF  98304     // float[4096]     16384
#define SELLM_OFF  114688    // float[40960]    163840
#define MASK_OFF   278528    // u64[4096*64]    2097152
#define BINSEG_OFF 2375680   // u64[4096*384]   12582912

__device__ __forceinline__ int score_bin(float s) {
    u32 b = __float_as_uint(s);
    if (b >= 0x3F800000u) return 0;
    int bin = (int)((0x3F800000u - b) >> 9);
    return bin > 4095 ? 4095 : bin;
}

// K0: zero binCnt + validw/nzw
__global__ void k_zero(u32* __restrict__ binCnt, u64* __restrict__ validw,
                       u64* __restrict__ nzw) {
    int i = blockIdx.x * 256 + threadIdx.x;
    binCnt[i] = 0u;
    if (i < 64) { validw[i] = 0ull; nzw[i] = 0ull; }
}

// K1: single conf scan, candidates scattered directly into per-bin segments.
__global__ void __launch_bounds__(256) k_compact(
        const float4* __restrict__ conf4, int N2,
        u32* __restrict__ binCnt, u64* __restrict__ binseg) {
    int stride = gridDim.x * 256;
    for (int i = blockIdx.x * 256 + threadIdx.x; i < N2; i += stride) {
        float4 v = conf4[i];
        if (v.y > CONF_T) {
            int b = score_bin(v.y);
            u32 p = atomicAdd(&binCnt[b], 1u);
            if (p < CAP)
                binseg[(size_t)b * CAP + p] =
                    ((u64)__float_as_uint(v.y) << 32) | (u64)(~(u32)(2 * i));
        }
        if (v.w > CONF_T) {
            int b = score_bin(v.w);
            u32 p = atomicAdd(&binCnt[b], 1u);
            if (p < CAP)
                binseg[(size_t)b * CAP + p] =
                    ((u64)__float_as_uint(v.w) << 32) | (u64)(~(u32)(2 * i + 1));
        }
    }
}

// K2: per-block redundant prefix scan of binCnt in LDS, then exact rank within
// bin + decode + scatter to rank position; threads beyond M zero-pad.
__global__ void __launch_bounds__(256) k_rankscan(
        const float4* __restrict__ loc, const float4* __restrict__ priors,
        const float* __restrict__ landm, const u32* __restrict__ binCnt,
        const u64* __restrict__ binseg,
        float4* __restrict__ selbox, float* __restrict__ selscore,
        float* __restrict__ sellm) {
    __shared__ u32 pref_s[4097];
    __shared__ u32 parts[256];
    __shared__ u32 m_sh;
    int t = threadIdx.x;
    u32 h[16];
    u32 sum = 0;
    #pragma unroll
    for (int i = 0; i < 16; i++) {
        u32 c = binCnt[t * 16 + i];
        h[i] = c > CAP ? CAP : c;
        sum += h[i];
    }
    parts[t] = sum;
    if (t == 0) m_sh = 0u;
    __syncthreads();
    for (int d = 1; d < 256; d <<= 1) {
        u32 add = (t >= d) ? parts[t - d] : 0u;
        __syncthreads();
        parts[t] += add;
        __syncthreads();
    }
    u32 incl = parts[t];
    u32 excl = incl - sum;
    u32 run = excl;
    #pragma unroll
    for (int i = 0; i < 16; i++) { pref_s[t * 16 + i] = run; run += h[i]; }
    if (t == 255) pref_s[4096] = run;   // total
    __syncthreads();
    u32 total = pref_s[4096];
    u32 target = total < TOPK ? total : TOPK;
    if (total > 0 && excl < target && incl >= target) {
        u32 r2 = excl;
        #pragma unroll
        for (int i = 0; i < 16; i++) {
            r2 += h[i];
            if (r2 >= target) { m_sh = r2; break; }
        }
    }
    __syncthreads();
    u32 M = m_sh;
    u32 p = blockIdx.x * 256 + t;
    if (p >= M) {
        if (p < TOPK) {   // zero-pad unused ranks
            selbox[p] = make_float4(0.f, 0.f, 0.f, 0.f);
            selscore[p] = 0.f;
            #pragma unroll
            for (int q = 0; q < 10; q++) sellm[(size_t)p * 10 + q] = 0.f;
        }
        return;
    }
    int lo = 0, hi = 4095;   // largest bin with pref_s[bin] <= p
    while (lo < hi) {
        int mid = (lo + hi + 1) >> 1;
        if (pref_s[mid] <= p) lo = mid; else hi = mid - 1;
    }
    u32 st = pref_s[lo];
    u32 cnt = pref_s[lo + 1] - st;
    const u64* seg = binseg + (size_t)lo * CAP;
    u64 key = seg[p - st];
    u32 rank = st;
    for (u32 j = 0; j < cnt; j++) rank += (seg[j] > key) ? 1u : 0u;
    if (rank >= TOPK) return;
    u32 idx = ~(u32)key;
    float sc = __uint_as_float((u32)(key >> 32));
    float4 L = loc[idx];
    float4 P = priors[idx];
    float cx = P.x + L.x * 0.1f * P.z;
    float cy = P.y + L.y * 0.1f * P.w;
    float wx = P.z * expf(L.z * 0.2f);
    float wy = P.w * expf(L.w * 0.2f);
    float4 bx;
    bx.x = (cx - 0.5f * wx) * 8192.f;
    bx.y = (cy - 0.5f * wy) * 8192.f;
    bx.z = (cx + 0.5f * wx) * 8192.f;
    bx.w = (cy + 0.5f * wy) * 8192.f;
    selbox[rank] = bx;
    selscore[rank] = sc;
    const float* lmr = landm + (size_t)idx * 10;
    float* lmo = sellm + (size_t)rank * 10;
    #pragma unroll
    for (int q = 0; q < 5; q++) {
        float lx = lmr[2 * q], ly = lmr[2 * q + 1];
        lmo[2 * q]     = (P.x + lx * 0.1f * P.z) * 8192.f;
        lmo[2 * q + 1] = (P.y + ly * 0.1f * P.w) * 8192.f;
    }
}

// K3: mask matrix, 512 threads (8 waves -> 2 waves/SIMD). Block b owns top rows
// 8b..8b+7 and bottom rows 4088-8b..4095-8b. Wave wv handles ONE top row
// rt=8b+wv and ONE bottom row rb=4088-8b+wv sharing a union column loop
// w in [b>>3, 64); bottom IoU guarded by wave-uniform w >= rbstart.
// Also ORs valid/nonzero bits and writes this block's 16 output rows.
__global__ void __launch_bounds__(512) k_maskout(
        const float4* __restrict__ selbox, const float* __restrict__ selscore,
        const float* __restrict__ sellm,
        u64* __restrict__ mask, u64* __restrict__ validw, u64* __restrict__ nzw,
        float* __restrict__ out) {
    __shared__ float4 sb[TOPK];   // 64 KB
    int t = threadIdx.x, b = blockIdx.x;
    for (int i = t; i < TOPK; i += 512) sb[i] = selbox[i];
    __syncthreads();
    int wv = t >> 6, lane = t & 63;
    int rt = b * 8 + wv;            // top row
    int rb = 4088 - 8 * b + wv;     // bottom row
    int wstart = b >> 3;            // = rt>>6
    int rbstart = 63 - wstart;      // = rb>>6
    float4 ra = sb[rt], rbb = sb[rb];
    float aa = fmaxf(ra.z - ra.x, 0.f) * fmaxf(ra.w - ra.y, 0.f);
    float ab = fmaxf(rbb.z - rbb.x, 0.f) * fmaxf(rbb.w - rbb.y, 0.f);
    u64 w0 = 0ull, w1 = 0ull;
    for (int w = wstart; w < 64; w++) {
        int j = w * 64 + lane;
        float4 bj = sb[j];
        float aj = fmaxf(bj.z - bj.x, 0.f) * fmaxf(bj.w - bj.y, 0.f);
        float lx0 = fmaxf(ra.x, bj.x), ly0 = fmaxf(ra.y, bj.y);
        float rx0 = fminf(ra.z, bj.z), ry0 = fminf(ra.w, bj.w);
        float in0 = fmaxf(rx0 - lx0, 0.f) * fmaxf(ry0 - ly0, 0.f);
        float iou0 = in0 / (aa + aj - in0 + 1e-12f);
        u64 bb0 = __ballot((j > rt) && (iou0 > IOU_T));
        if (lane == w) w0 = bb0;
        if (w >= rbstart) {         // wave-uniform guard: bottom row's range
            float lx1 = fmaxf(rbb.x, bj.x), ly1 = fmaxf(rbb.y, bj.y);
            float rx1 = fminf(rbb.z, bj.z), ry1 = fminf(rbb.w, bj.w);
            float in1 = fmaxf(rx1 - lx1, 0.f) * fmaxf(ry1 - ly1, 0.f);
            float iou1 = in1 / (ab + aj - in1 + 1e-12f);
            u64 bb1 = __ballot((j > rb) && (iou1 > IOU_T));
            if (lane == w) w1 = bb1;
        }
    }
    mask[(size_t)rt * 64 + lane] = w0;   // zeros for lane < wstart
    mask[(size_t)rb * 64 + lane] = w1;   // zeros for lane < rbstart
    u64 nzt = __ballot(w0 != 0ull);
    u64 nzb = __ballot(w1 != 0ull);
    if (lane == 0) {
        if (selscore[rt] > CONF_T) atomicOr(&validw[rt >> 6], 1ull << (rt & 63));
        if (nzt)                   atomicOr(&nzw[rt >> 6], 1ull << (rt & 63));
        if (selscore[rb] > CONF_T) atomicOr(&validw[rb >> 6], 1ull << (rb & 63));
        if (nzb)                   atomicOr(&nzw[rb >> 6], 1ull << (rb & 63));
    }
    // unconditional output write for this block's 16 rows (nms zeroes later)
    if (t < 240) {
        int ri = t / 15;
        int col = t - ri * 15;
        int row = (ri < 8) ? (b * 8 + ri) : (4088 - 8 * b + (ri - 8));
        const float* sbf = (const float*)selbox;
        float val;
        if (col < 4)       val = sbf[row * 4 + col];
        else if (col == 4) val = selscore[row];
        else               val = sellm[(size_t)row * 10 + (col - 5)];
        out[(size_t)row * 15 + col] = val;
    }
}

// K4: serial greedy NMS (wave 0) + zeroing of non-kept rows (all 16 waves)
__global__ void __launch_bounds__(1024) k_nmszero(
        const u64* __restrict__ mask, const u64* __restrict__ validw_arr,
        const u64* __restrict__ nzw_arr, float* __restrict__ out) {
    __shared__ u64 keep_s[64];
    int tid = threadIdx.x;
    if (tid < 64) {
        int t = tid;
        u64 vw = validw_arr[t];
        u64 nzv = nzw_arr[t];
        u64 sup = 0ull, keepw = 0ull;
        for (int g = 0; g < 64; g++) {
            u64 cur = __shfl(sup, g);
            u64 validg = __shfl(vw, g);
            u64 nzg = __shfl(nzv, g);
            u64 alive = (~cur) & validg;
            if (nzg) {
                u64 intra = mask[(size_t)(g * 64 + t) * 64 + g];
                u64 rem = nzg;
                while (rem) {
                    int bb = __ffsll((long long)rem) - 1;
                    rem &= rem - 1;
                    if ((alive >> bb) & 1ull) {
                        u64 rowb = __shfl(intra, bb);
                        alive &= ~rowb;
                    }
                }
            }
            if (t == g) keepw = alive;
            u64 srem = alive & nzg;
            const u64* mb = mask + (size_t)(g * 64) * 64 + t;
            while (srem) {
                int i0, i1 = -1, i2 = -1, i3 = -1, i4 = -1, i5 = -1, i6 = -1, i7 = -1;
                i0 = __ffsll((long long)srem) - 1; srem &= srem - 1;
                if (srem) { i1 = __ffsll((long long)srem) - 1; srem &= srem - 1;
                if (srem) { i2 = __ffsll((long long)srem) - 1; srem &= srem - 1;
                if (srem) { i3 = __ffsll((long long)srem) - 1; srem &= srem - 1;
                if (srem) { i4 = __ffsll((long long)srem) - 1; srem &= srem - 1;
                if (srem) { i5 = __ffsll((long long)srem) - 1; srem &= srem - 1;
                if (srem) { i6 = __ffsll((long long)srem) - 1; srem &= srem - 1;
                if (srem) { i7 = __ffsll((long long)srem) - 1; srem &= srem - 1; } } } } } } }
                u64 a0 = mb[(size_t)i0 * 64];
                u64 a1 = (i1 >= 0) ? mb[(size_t)i1 * 64] : 0ull;
                u64 a2 = (i2 >= 0) ? mb[(size_t)i2 * 64] : 0ull;
                u64 a3 = (i3 >= 0) ? mb[(size_t)i3 * 64] : 0ull;
                u64 a4 = (i4 >= 0) ? mb[(size_t)i4 * 64] : 0ull;
                u64 a5 = (i5 >= 0) ? mb[(size_t)i5 * 64] : 0ull;
                u64 a6 = (i6 >= 0) ? mb[(size_t)i6 * 64] : 0ull;
                u64 a7 = (i7 >= 0) ? mb[(size_t)i7 * 64] : 0ull;
                sup |= (a0 | a1) | (a2 | a3) | ((a4 | a5) | (a6 | a7));
            }
        }
        keep_s[t] = keepw;
    }
    __syncthreads();
    for (int r = tid; r < TOPK; r += 1024) {
        if (!((keep_s[r >> 6] >> (r & 63)) & 1ull)) {
            float* o = out + (size_t)r * 15;
            #pragma unroll
            for (int q = 0; q < 15; q++) o[q] = 0.f;
        }
    }
}

extern "C" void kernel_launch(void* const* d_in, const int* in_sizes, int n_in,
                              void* d_out, int out_size, void* d_ws, size_t ws_size,
                              hipStream_t stream) {
    const float4* loc    = (const float4*)d_in[0];
    const float4* conf4  = (const float4*)d_in[1];
    const float*  landm  = (const float*)d_in[2];
    const float4* priors = (const float4*)d_in[3];
    float* out = (float*)d_out;
    int N = in_sizes[1] / 2;
    int N2 = N / 2;   // float4 elements (2 anchors each)

    char* ws = (char*)d_ws;
    u32* binCnt   = (u32*)(ws + BINCNT_OFF);
    u64* validw   = (u64*)(ws + VALIDW_OFF);
    u64* nzw      = (u64*)(ws + NZW_OFF);
    float4* selbox = (float4*)(ws + SELBOX_OFF);
    float* selsc   = (float*)(ws + SELSC_OFF);
    float* sellm   = (float*)(ws + SELLM_OFF);
    u64* maskp    = (u64*)(ws + MASK_OFF);
    u64* binseg   = (u64*)(ws + BINSEG_OFF);

    k_zero<<<16, 256, 0, stream>>>(binCnt, validw, nzw);
    k_compact<<<2048, 256, 0, stream>>>(conf4, N2, binCnt, binseg);
    k_rankscan<<<32, 256, 0, stream>>>(loc, priors, landm, binCnt, binseg,
                                       selbox, selsc, sellm);
    k_maskout<<<256, 512, 0, stream>>>(selbox, selsc, sellm, maskp, validw, nzw, out);
    k_nmszero<<<1, 1024, 0, stream>>>(maskp, validw, nzw, out);
}